// Round 1
// baseline (571.191 us; speedup 1.0000x reference)
//
#include <hip/hip_runtime.h>
#include <hip/hip_bf16.h>

// MultiPrecisionLinear: out[m, o] = sum_i x[m, i] * W[bits[path(m)], o, i] + bias[o]
// M = 262144 (8 paths x 32768 rows), K = Din = 256, N = Dout = 256.
// Memory-bound: 537 MB HBM traffic -> ~85 us floor. bf16 MFMA for compute.

typedef float  floatx4  __attribute__((ext_vector_type(4)));
typedef short  shortx8  __attribute__((ext_vector_type(8)));
typedef unsigned short ushortx4 __attribute__((ext_vector_type(4)));

constexpr int DIN  = 256;
constexpr int DOUT = 256;
constexpr int ROWS_PER_PATH = 8 * 4096;   // bpp * S
constexpr int BM   = 64;                  // M-rows per block
constexpr int BK   = 64;                  // K-chunk
constexpr int LDSK = BK + 8;              // pad: 144 B stride = 16B-aligned, banks shift 4/row

__device__ __forceinline__ unsigned short f2bf(float f) {
  // round-to-nearest-even fp32 -> bf16 (inputs are finite gaussians; no NaN path needed)
  union { float f; unsigned u; } c; c.f = f;
  unsigned r = c.u + 0x7fffu + ((c.u >> 16) & 1u);
  return (unsigned short)(r >> 16);
}

__global__ __launch_bounds__(256, 2)
void mp_linear_kernel(const float* __restrict__ x,
                      const float* __restrict__ wbank,
                      const float* __restrict__ bias,
                      const int*   __restrict__ bits,
                      float* __restrict__ out) {
  __shared__ unsigned short xs[BM * LDSK];     //  9.2 KB
  __shared__ unsigned short ws[DOUT * LDSK];   // 36.9 KB  (total 46 KB -> 3 blocks/CU by LDS)

  const int tid  = threadIdx.x;
  const int row0 = blockIdx.x * BM;
  const int path = row0 / ROWS_PER_PATH;
  const float* __restrict__ W = wbank + (size_t)bits[path] * (DOUT * DIN);

  const int lane = tid & 63;
  const int wave = tid >> 6;
  const int n0   = wave * 64;       // wave's N offset (4 waves cover N=256)
  const int quad = lane >> 4;
  const int l16  = lane & 15;

  floatx4 acc[4][4];
#pragma unroll
  for (int i = 0; i < 4; ++i)
#pragma unroll
    for (int j = 0; j < 4; ++j)
      acc[i][j] = (floatx4)0.f;

  for (int k0 = 0; k0 < DIN; k0 += BK) {
    // ---- stage x tile: 64 rows x 64 k, fp32 -> bf16. 1024 float4, 4 per thread.
#pragma unroll
    for (int i = 0; i < 4; ++i) {
      const int f  = tid + i * 256;
      const int r  = f >> 4;          // row in tile
      const int kq = f & 15;          // float4 index within row
      const floatx4 v = *(const floatx4*)(x + (size_t)(row0 + r) * DIN + k0 + kq * 4);
      ushortx4 h;
      h.x = f2bf(v.x); h.y = f2bf(v.y); h.z = f2bf(v.z); h.w = f2bf(v.w);
      *(ushortx4*)&xs[r * LDSK + kq * 4] = h;
    }
    // ---- stage W tile: 256 out-rows x 64 k, fp32 -> bf16. 4096 float4, 16 per thread.
#pragma unroll
    for (int i = 0; i < 16; ++i) {
      const int f  = tid + i * 256;
      const int r  = f >> 4;
      const int kq = f & 15;
      const floatx4 v = *(const floatx4*)(W + (size_t)r * DIN + k0 + kq * 4);
      ushortx4 h;
      h.x = f2bf(v.x); h.y = f2bf(v.y); h.z = f2bf(v.z); h.w = f2bf(v.w);
      *(ushortx4*)&ws[r * LDSK + kq * 4] = h;
    }
    __syncthreads();

    // ---- compute: 2 k-steps of 16x16x32 bf16 MFMA, 4x4 fragments per wave
#pragma unroll
    for (int ks = 0; ks < 2; ++ks) {
      const int krd = ks * 32 + quad * 8;   // A/B layout: [m|n = lane&15][k = quad*8 + j]
      shortx8 a[4], b[4];
#pragma unroll
      for (int mf = 0; mf < 4; ++mf)
        a[mf] = *(const shortx8*)&xs[(mf * 16 + l16) * LDSK + krd];
#pragma unroll
      for (int nf = 0; nf < 4; ++nf)
        b[nf] = *(const shortx8*)&ws[(n0 + nf * 16 + l16) * LDSK + krd];
#pragma unroll
      for (int mf = 0; mf < 4; ++mf)
#pragma unroll
        for (int nf = 0; nf < 4; ++nf)
          acc[mf][nf] = __builtin_amdgcn_mfma_f32_16x16x32_bf16(a[mf], b[nf], acc[mf][nf], 0, 0, 0);
    }
    __syncthreads();
  }

  // ---- epilogue: + bias, fp32 store. C/D layout (m89/m91): col = lane&15, row = quad*4 + reg.
  float bv[4];
#pragma unroll
  for (int nf = 0; nf < 4; ++nf)
    bv[nf] = bias[n0 + nf * 16 + l16];

#pragma unroll
  for (int mf = 0; mf < 4; ++mf) {
    const int rbase = row0 + mf * 16 + quad * 4;
#pragma unroll
    for (int nf = 0; nf < 4; ++nf) {
      const int col = n0 + nf * 16 + l16;
      float* o = out + (size_t)rbase * DOUT + col;
#pragma unroll
      for (int r = 0; r < 4; ++r)
        o[(size_t)r * DOUT] = acc[mf][nf][r] + bv[nf];
    }
  }
}

extern "C" void kernel_launch(void* const* d_in, const int* in_sizes, int n_in,
                              void* d_out, int out_size, void* d_ws, size_t ws_size,
                              hipStream_t stream) {
  const float* x     = (const float*)d_in[0];
  const float* wbank = (const float*)d_in[1];
  const float* bias  = (const float*)d_in[2];
  const int*   bits  = (const int*)d_in[3];
  float*       out   = (float*)d_out;

  const int total_rows = in_sizes[0] / DIN;   // 262144
  const int grid = total_rows / BM;           // 4096
  mp_linear_kernel<<<grid, 256, 0, stream>>>(x, wbank, bias, bits, out);
}

// Round 2
// 555.839 us; speedup vs baseline: 1.0276x; 1.0276x over previous
//
#include <hip/hip_runtime.h>

// MultiPrecisionLinear: out[m,o] = sum_i x[m,i] * W[bits[path(m)],o,i] + bias[o]
// M = 262144 (8 paths x 32768 rows), K = 256, N = 256, fp32 in/out.
// Round 2: LDS-free. A-frags loaded fp32 from global + reg convert (L1-reuse
// across the 4 waves of a block); B-frags from a bf16 weight bank pre-converted
// once into d_ws. Zero barriers, zero LDS -> occupancy 50%, latency-tolerant.

typedef float  floatx4  __attribute__((ext_vector_type(4)));
typedef short  shortx8  __attribute__((ext_vector_type(8)));
typedef unsigned short ushortx4 __attribute__((ext_vector_type(4)));

constexpr int DIN  = 256;
constexpr int DOUT = 256;
constexpr int ROWS_PER_PATH = 8 * 4096;   // bpp * S
constexpr int BM   = 64;                  // rows per block (4 waves x full N=256)
constexpr int WBANK_ELEMS = 7 * DOUT * DIN;

__device__ __forceinline__ unsigned short f2bf(float f) {
  // round-to-nearest-even fp32 -> bf16
  union { float f; unsigned u; } c; c.f = f;
  unsigned r = c.u + 0x7fffu + ((c.u >> 16) & 1u);
  return (unsigned short)(r >> 16);
}

__device__ __forceinline__ shortx8 cvt8(floatx4 v0, floatx4 v1) {
  shortx8 h;
  h[0] = (short)f2bf(v0.x); h[1] = (short)f2bf(v0.y);
  h[2] = (short)f2bf(v0.z); h[3] = (short)f2bf(v0.w);
  h[4] = (short)f2bf(v1.x); h[5] = (short)f2bf(v1.y);
  h[6] = (short)f2bf(v1.z); h[7] = (short)f2bf(v1.w);
  return h;
}

// one-time fp32 -> bf16 conversion of the 7-entry weight bank into d_ws
__global__ void convert_w_kernel(const float* __restrict__ w,
                                 unsigned short* __restrict__ o, int n4) {
  int i = blockIdx.x * 256 + threadIdx.x;
  if (i < n4) {
    floatx4 v = ((const floatx4*)w)[i];
    ushortx4 h;
    h.x = f2bf(v.x); h.y = f2bf(v.y); h.z = f2bf(v.z); h.w = f2bf(v.w);
    ((ushortx4*)o)[i] = h;
  }
}

template <bool WBF>
__global__ __launch_bounds__(256, 4)
void mp_linear_kernel(const float* __restrict__ x,
                      const void*  __restrict__ wsel,
                      const float* __restrict__ bias,
                      const int*   __restrict__ bits,
                      float* __restrict__ out) {
  const int tid  = threadIdx.x;
  const int row0 = blockIdx.x * BM;
  const int path = row0 / ROWS_PER_PATH;
  const int widx = bits[path];

  const int lane = tid & 63;
  const int wave = tid >> 6;
  const int n0   = wave * 64;       // wave's N offset (4 waves cover N=256)
  const int quad = lane >> 4;
  const int l16  = lane & 15;

  // per-lane base pointers: A[m=l16][k=quad*8+j], B[n=l16][k=quad*8+j]
  const float* __restrict__ xp = x + (size_t)(row0 + l16) * DIN + quad * 8;
  const unsigned short* __restrict__ wbf =
      (const unsigned short*)wsel + (size_t)widx * (DOUT * DIN)
      + (size_t)(n0 + l16) * DIN + quad * 8;
  const float* __restrict__ wf32 =
      (const float*)wsel + (size_t)widx * (DOUT * DIN)
      + (size_t)(n0 + l16) * DIN + quad * 8;

  floatx4 acc[4][4];
#pragma unroll
  for (int i = 0; i < 4; ++i)
#pragma unroll
    for (int j = 0; j < 4; ++j)
      acc[i][j] = (floatx4)0.f;

#pragma unroll 2
  for (int k0 = 0; k0 < DIN; k0 += 32) {
    shortx8 a[4], b[4];
#pragma unroll
    for (int mf = 0; mf < 4; ++mf) {
      const float* p = xp + (size_t)(mf * 16) * DIN + k0;
      a[mf] = cvt8(*(const floatx4*)p, *(const floatx4*)(p + 4));
    }
#pragma unroll
    for (int nf = 0; nf < 4; ++nf) {
      if (WBF) {
        b[nf] = *(const shortx8*)(wbf + (size_t)(nf * 16) * DIN + k0);
      } else {
        const float* p = wf32 + (size_t)(nf * 16) * DIN + k0;
        b[nf] = cvt8(*(const floatx4*)p, *(const floatx4*)(p + 4));
      }
    }
#pragma unroll
    for (int mf = 0; mf < 4; ++mf)
#pragma unroll
      for (int nf = 0; nf < 4; ++nf)
        acc[mf][nf] = __builtin_amdgcn_mfma_f32_16x16x32_bf16(a[mf], b[nf], acc[mf][nf], 0, 0, 0);
  }

  // epilogue: + bias, fp32 store. C/D layout (m89/m91): col = lane&15, row = quad*4 + reg.
  float bv[4];
#pragma unroll
  for (int nf = 0; nf < 4; ++nf)
    bv[nf] = bias[n0 + nf * 16 + l16];

#pragma unroll
  for (int mf = 0; mf < 4; ++mf) {
    const int rbase = row0 + mf * 16 + quad * 4;
#pragma unroll
    for (int nf = 0; nf < 4; ++nf) {
      const int col = n0 + nf * 16 + l16;
      float* o = out + (size_t)rbase * DOUT + col;
#pragma unroll
      for (int r = 0; r < 4; ++r)
        o[(size_t)r * DOUT] = acc[mf][nf][r] + bv[nf];
    }
  }
}

extern "C" void kernel_launch(void* const* d_in, const int* in_sizes, int n_in,
                              void* d_out, int out_size, void* d_ws, size_t ws_size,
                              hipStream_t stream) {
  const float* x     = (const float*)d_in[0];
  const float* wbank = (const float*)d_in[1];
  const float* bias  = (const float*)d_in[2];
  const int*   bits  = (const int*)d_in[3];
  float*       out   = (float*)d_out;

  const int total_rows = in_sizes[0] / DIN;   // 262144
  const int grid = total_rows / BM;           // 4096

  const size_t wbf_bytes = (size_t)WBANK_ELEMS * sizeof(unsigned short);  // 917504
  if (ws_size >= wbf_bytes) {
    unsigned short* wbf = (unsigned short*)d_ws;
    const int n4 = WBANK_ELEMS / 4;           // 114688
    convert_w_kernel<<<(n4 + 255) / 256, 256, 0, stream>>>(wbank, wbf, n4);
    mp_linear_kernel<true><<<grid, 256, 0, stream>>>(x, wbf, bias, bits, out);
  } else {
    mp_linear_kernel<false><<<grid, 256, 0, stream>>>(x, wbank, bias, bits, out);
  }
}